// Round 1
// baseline (384.986 us; speedup 1.0000x reference)
//
#include <hip/hip_runtime.h>
#include <stdint.h>

#define SB 2048
#define DB 1024
#define NHB 16
#define DHB 64

typedef __attribute__((ext_vector_type(8))) short short8;
typedef __attribute__((ext_vector_type(4))) float f32x4;

__device__ __forceinline__ unsigned short f2bf(float f) {
  union { float f; uint32_t u; } v; v.f = f;
  uint32_t u = v.u;
  return (unsigned short)((u + 0x7FFFu + ((u >> 16) & 1u)) >> 16);
}

// ---------------- K1: Y_heads = head_split(X @ W.T), bf16 out ----------------
// X: (4096 x 1024) fp32 row-major (rows = b*S+s). W: (1024 x 1024) fp32.
// Yh: (B*nh, S, dh) bf16. grid (64,16), block 256.
__global__ __launch_bounds__(256) void proj_kernel(
    const float* __restrict__ X, const float* __restrict__ W,
    unsigned short* __restrict__ Yh)
{
  __shared__ unsigned short Alds[64][40];
  __shared__ unsigned short Blds[64][40];
  const int tid = threadIdx.x;
  const int wave = tid >> 6, lane = tid & 63;
  const int g = lane >> 4, li = lane & 15;
  const int m0 = blockIdx.x * 64, n0 = blockIdx.y * 64;
  const int lr = tid >> 2, lseg = tid & 3;

  f32x4 acc[4];
  #pragma unroll
  for (int i = 0; i < 4; ++i)
    #pragma unroll
    for (int j = 0; j < 4; ++j) acc[i][j] = 0.f;

  for (int k0 = 0; k0 < DB; k0 += 32) {
    __syncthreads();
    {
      const float* sa = X + (size_t)(m0 + lr) * DB + k0 + lseg * 8;
      const float* sb = W + (size_t)(n0 + lr) * DB + k0 + lseg * 8;
      short8 ta, tb;
      #pragma unroll
      for (int j = 0; j < 8; ++j) {
        ta[j] = (short)f2bf(sa[j]);
        tb[j] = (short)f2bf(sb[j]);
      }
      *(short8*)&Alds[lr][lseg * 8] = ta;
      *(short8*)&Blds[lr][lseg * 8] = tb;
    }
    __syncthreads();
    short8 a = *(const short8*)&Alds[wave * 16 + li][g * 8];
    #pragma unroll
    for (int nf = 0; nf < 4; ++nf) {
      short8 b = *(const short8*)&Blds[nf * 16 + li][g * 8];
      acc[nf] = __builtin_amdgcn_mfma_f32_16x16x32_bf16(a, b, acc[nf], 0, 0, 0);
    }
  }
  #pragma unroll
  for (int nf = 0; nf < 4; ++nf)
    #pragma unroll
    for (int r = 0; r < 4; ++r) {
      int row = m0 + wave * 16 + g * 4 + r;   // global row in 0..4095
      int col = n0 + nf * 16 + li;            // output channel 0..1023
      int b_ = row >> 11, s_ = row & 2047;
      int h = col >> 6, dp = col & 63;
      Yh[((size_t)(b_ * NHB + h) * SB + s_) * DHB + dp] = f2bf(acc[nf][r]);
    }
}

// ---------------- K2: flash-style attention + attn materialization ----------
// grid (32 qtiles, 32 bh), block 256 (4 waves; wave owns 16 q-rows of a 64-row tile)
__global__ __launch_bounds__(256) void attn_kernel(
    const unsigned short* __restrict__ Qh, const unsigned short* __restrict__ Kh,
    const unsigned short* __restrict__ Vh, const int* __restrict__ valid_len,
    float* __restrict__ attn_out, unsigned short* __restrict__ Mg)
{
  __shared__ unsigned short Qlds[64][72];
  __shared__ unsigned short Klds[64][72];
  __shared__ unsigned short Vtlds[64][72];
  __shared__ unsigned short Plds[64][72];

  const int tid = threadIdx.x;
  const int wave = tid >> 6, lane = tid & 63;
  const int g = lane >> 4, li = lane & 15;
  const int q0 = blockIdx.x * 64;
  const int bh = blockIdx.y;
  const int b_ = bh >> 4;
  const int vl = valid_len[b_];
  const int lr = tid >> 2, lseg = tid & 3;

  // stage Q tile once (64 rows x 64 dh, bf16)
  {
    const unsigned short* src = Qh + ((size_t)bh * SB + q0 + lr) * DHB + lseg * 16;
    *(short8*)&Qlds[lr][lseg * 16]     = *(const short8*)src;
    *(short8*)&Qlds[lr][lseg * 16 + 8] = *(const short8*)(src + 8);
  }
  __syncthreads();

  short8 qa[2];
  qa[0] = *(const short8*)&Qlds[wave * 16 + li][g * 8];
  qa[1] = *(const short8*)&Qlds[wave * 16 + li][32 + g * 8];

  float mrow[4], lrow[4];
  #pragma unroll
  for (int r = 0; r < 4; ++r) { mrow[r] = -1e30f; lrow[r] = 0.f; }

  // ---- pass 1: online (m, l) ----
  for (int kt = 0; kt < SB; kt += 64) {
    __syncthreads();
    {
      const unsigned short* src = Kh + ((size_t)bh * SB + kt + lr) * DHB + lseg * 16;
      *(short8*)&Klds[lr][lseg * 16]     = *(const short8*)src;
      *(short8*)&Klds[lr][lseg * 16 + 8] = *(const short8*)(src + 8);
    }
    __syncthreads();
    f32x4 sc[4];
    #pragma unroll
    for (int nf = 0; nf < 4; ++nf)
      #pragma unroll
      for (int j = 0; j < 4; ++j) sc[nf][j] = 0.f;
    #pragma unroll
    for (int ks = 0; ks < 2; ++ks)
      #pragma unroll
      for (int nf = 0; nf < 4; ++nf) {
        short8 b = *(const short8*)&Klds[nf * 16 + li][ks * 32 + g * 8];
        sc[nf] = __builtin_amdgcn_mfma_f32_16x16x32_bf16(qa[ks], b, sc[nf], 0, 0, 0);
      }
    float tmax[4] = {-1e30f, -1e30f, -1e30f, -1e30f};
    #pragma unroll
    for (int nf = 0; nf < 4; ++nf)
      #pragma unroll
      for (int r = 0; r < 4; ++r) {
        int key = kt + nf * 16 + li;
        float s = sc[nf][r] * 0.125f;
        if (key >= vl) s = -1e6f;
        sc[nf][r] = s;
        tmax[r] = fmaxf(tmax[r], s);
      }
    #pragma unroll
    for (int r = 0; r < 4; ++r) {
      for (int d = 1; d < 16; d <<= 1)
        tmax[r] = fmaxf(tmax[r], __shfl_xor(tmax[r], d));
      float mnew = fmaxf(mrow[r], tmax[r]);
      float ssum = 0.f;
      #pragma unroll
      for (int nf = 0; nf < 4; ++nf) ssum += __expf(sc[nf][r] - mnew);
      for (int d = 1; d < 16; d <<= 1) ssum += __shfl_xor(ssum, d);
      lrow[r] = lrow[r] * __expf(mrow[r] - mnew) + ssum;
      mrow[r] = mnew;
    }
  }

  float rl[4];
  #pragma unroll
  for (int r = 0; r < 4; ++r) rl[r] = 1.f / lrow[r];

  f32x4 oacc[4];
  #pragma unroll
  for (int i = 0; i < 4; ++i)
    #pragma unroll
    for (int j = 0; j < 4; ++j) oacc[i][j] = 0.f;

  // ---- pass 2: p, attn write, PV ----
  for (int kt = 0; kt < SB; kt += 64) {
    __syncthreads();
    {
      const unsigned short* src = Kh + ((size_t)bh * SB + kt + lr) * DHB + lseg * 16;
      *(short8*)&Klds[lr][lseg * 16]     = *(const short8*)src;
      *(short8*)&Klds[lr][lseg * 16 + 8] = *(const short8*)(src + 8);
      const unsigned short* vs = Vh + ((size_t)bh * SB + kt + lr) * DHB + lseg * 16;
      short8 v0 = *(const short8*)vs;
      short8 v1 = *(const short8*)(vs + 8);
      #pragma unroll
      for (int j = 0; j < 8; ++j) {
        Vtlds[lseg * 16 + j][lr]     = (unsigned short)v0[j];
        Vtlds[lseg * 16 + 8 + j][lr] = (unsigned short)v1[j];
      }
    }
    __syncthreads();
    f32x4 sc[4];
    #pragma unroll
    for (int nf = 0; nf < 4; ++nf)
      #pragma unroll
      for (int j = 0; j < 4; ++j) sc[nf][j] = 0.f;
    #pragma unroll
    for (int ks = 0; ks < 2; ++ks)
      #pragma unroll
      for (int nf = 0; nf < 4; ++nf) {
        short8 b = *(const short8*)&Klds[nf * 16 + li][ks * 32 + g * 8];
        sc[nf] = __builtin_amdgcn_mfma_f32_16x16x32_bf16(qa[ks], b, sc[nf], 0, 0, 0);
      }
    #pragma unroll
    for (int nf = 0; nf < 4; ++nf)
      #pragma unroll
      for (int r = 0; r < 4; ++r) {
        int key = kt + nf * 16 + li;
        float s = sc[nf][r] * 0.125f;
        if (key >= vl) s = -1e6f;
        float p = __expf(s - mrow[r]) * rl[r];
        sc[nf][r] = p;
      }
    // write normalized attn (fp32) + P tile (bf16) to LDS
    #pragma unroll
    for (int nf = 0; nf < 4; ++nf)
      #pragma unroll
      for (int r = 0; r < 4; ++r) {
        int qrow = q0 + wave * 16 + g * 4 + r;
        int key = kt + nf * 16 + li;
        attn_out[(size_t)bh * SB * SB + (size_t)qrow * SB + key] = sc[nf][r];
        Plds[wave * 16 + g * 4 + r][nf * 16 + li] = f2bf(sc[nf][r]);
      }
    __syncthreads();
    // PV: oacc += P(16x64) @ V(64x64)
    #pragma unroll
    for (int ks = 0; ks < 2; ++ks) {
      short8 pa = *(const short8*)&Plds[wave * 16 + li][ks * 32 + g * 8];
      #pragma unroll
      for (int nf = 0; nf < 4; ++nf) {
        short8 vb = *(const short8*)&Vtlds[nf * 16 + li][ks * 32 + g * 8];
        oacc[nf] = __builtin_amdgcn_mfma_f32_16x16x32_bf16(pa, vb, oacc[nf], 0, 0, 0);
      }
    }
  }

  // epilogue: merged[b, s, d'*nh + h] = O  (faithful Merge_base_head permutation)
  #pragma unroll
  for (int nf = 0; nf < 4; ++nf)
    #pragma unroll
    for (int r = 0; r < 4; ++r) {
      int qrow = q0 + wave * 16 + g * 4 + r;
      int dp = nf * 16 + li;
      int h = bh & 15;
      Mg[((size_t)b_ * SB + qrow) * DB + dp * NHB + h] = f2bf(oacc[nf][r]);
    }
}

// ---------------- K3: out = merged @ Wo.T, fp32 out ----------------
__global__ __launch_bounds__(256) void outproj_kernel(
    const unsigned short* __restrict__ Mg, const float* __restrict__ W,
    float* __restrict__ Out)
{
  __shared__ unsigned short Alds[64][40];
  __shared__ unsigned short Blds[64][40];
  const int tid = threadIdx.x;
  const int wave = tid >> 6, lane = tid & 63;
  const int g = lane >> 4, li = lane & 15;
  const int m0 = blockIdx.x * 64, n0 = blockIdx.y * 64;
  const int lr = tid >> 2, lseg = tid & 3;

  f32x4 acc[4];
  #pragma unroll
  for (int i = 0; i < 4; ++i)
    #pragma unroll
    for (int j = 0; j < 4; ++j) acc[i][j] = 0.f;

  for (int k0 = 0; k0 < DB; k0 += 32) {
    __syncthreads();
    {
      const unsigned short* sa = Mg + (size_t)(m0 + lr) * DB + k0 + lseg * 8;
      *(short8*)&Alds[lr][lseg * 8] = *(const short8*)sa;
      const float* sb = W + (size_t)(n0 + lr) * DB + k0 + lseg * 8;
      short8 tb;
      #pragma unroll
      for (int j = 0; j < 8; ++j) tb[j] = (short)f2bf(sb[j]);
      *(short8*)&Blds[lr][lseg * 8] = tb;
    }
    __syncthreads();
    short8 a = *(const short8*)&Alds[wave * 16 + li][g * 8];
    #pragma unroll
    for (int nf = 0; nf < 4; ++nf) {
      short8 b = *(const short8*)&Blds[nf * 16 + li][g * 8];
      acc[nf] = __builtin_amdgcn_mfma_f32_16x16x32_bf16(a, b, acc[nf], 0, 0, 0);
    }
  }
  #pragma unroll
  for (int nf = 0; nf < 4; ++nf)
    #pragma unroll
    for (int r = 0; r < 4; ++r) {
      int row = m0 + wave * 16 + g * 4 + r;
      int col = n0 + nf * 16 + li;
      Out[(size_t)row * DB + col] = acc[nf][r];
    }
}

extern "C" void kernel_launch(void* const* d_in, const int* in_sizes, int n_in,
                              void* d_out, int out_size, void* d_ws, size_t ws_size,
                              hipStream_t stream) {
  const float* q  = (const float*)d_in[0];
  const float* k  = (const float*)d_in[1];
  const float* v  = (const float*)d_in[2];
  const float* Wq = (const float*)d_in[3];
  const float* Wk = (const float*)d_in[4];
  const float* Wv = (const float*)d_in[5];
  const float* Wo = (const float*)d_in[6];
  const int* vlen = (const int*)d_in[7];

  const size_t hsz = (size_t)2 * NHB * SB * DHB;  // 4,194,304 elems per tensor
  unsigned short* Qh = (unsigned short*)d_ws;
  unsigned short* Kh = Qh + hsz;
  unsigned short* Vh = Kh + hsz;
  unsigned short* Mg = Vh + hsz;

  float* out  = (float*)d_out;
  float* attn = out + (size_t)2 * SB * DB;

  dim3 blk(256);
  proj_kernel<<<dim3(64, 16), blk, 0, stream>>>(q, Wq, Qh);
  proj_kernel<<<dim3(64, 16), blk, 0, stream>>>(k, Wk, Kh);
  proj_kernel<<<dim3(64, 16), blk, 0, stream>>>(v, Wv, Vh);
  attn_kernel<<<dim3(32, 32), blk, 0, stream>>>(Qh, Kh, Vh, vlen, attn, Mg);
  outproj_kernel<<<dim3(64, 16), blk, 0, stream>>>(Mg, Wo, out);
}

// Round 2
// 282.665 us; speedup vs baseline: 1.3620x; 1.3620x over previous
//
#include <hip/hip_runtime.h>
#include <stdint.h>

#define SB 2048
#define DB 1024
#define NHB 16
#define DHB 64

typedef __attribute__((ext_vector_type(8))) short short8;
typedef __attribute__((ext_vector_type(4))) float f32x4;

__device__ __forceinline__ unsigned short f2bf(float f) {
  union { float f; uint32_t u; } v; v.f = f;
  uint32_t u = v.u;
  return (unsigned short)((u + 0x7FFFu + ((u >> 16) & 1u)) >> 16);
}

// ---------------- K1: projection. vt=0: Yh = head_split(X @ W.T) bf16.
//                  vt=1: Vt[bh][dp][s] = transposed head-split (for V).
// X: (4096 x 1024) fp32. W: (1024 x 1024) fp32. grid (64,16), block 256.
__global__ __launch_bounds__(256) void proj_kernel(
    const float* __restrict__ X, const float* __restrict__ W,
    unsigned short* __restrict__ Yh, int vt)
{
  __shared__ unsigned short Alds[64][40];
  __shared__ unsigned short Blds[64][40];
  __shared__ unsigned short Tlds[64][72];
  const int tid = threadIdx.x;
  const int wave = tid >> 6, lane = tid & 63;
  const int g = lane >> 4, li = lane & 15;
  const int m0 = blockIdx.x * 64, n0 = blockIdx.y * 64;
  const int lr = tid >> 2, lseg = tid & 3;

  f32x4 acc[4];
  #pragma unroll
  for (int i = 0; i < 4; ++i)
    #pragma unroll
    for (int j = 0; j < 4; ++j) acc[i][j] = 0.f;

  for (int k0 = 0; k0 < DB; k0 += 32) {
    __syncthreads();
    {
      const float* sa = X + (size_t)(m0 + lr) * DB + k0 + lseg * 8;
      const float* sb = W + (size_t)(n0 + lr) * DB + k0 + lseg * 8;
      short8 ta, tb;
      #pragma unroll
      for (int j = 0; j < 8; ++j) {
        ta[j] = (short)f2bf(sa[j]);
        tb[j] = (short)f2bf(sb[j]);
      }
      *(short8*)&Alds[lr][lseg * 8] = ta;
      *(short8*)&Blds[lr][lseg * 8] = tb;
    }
    __syncthreads();
    short8 a = *(const short8*)&Alds[wave * 16 + li][g * 8];
    #pragma unroll
    for (int nf = 0; nf < 4; ++nf) {
      short8 b = *(const short8*)&Blds[nf * 16 + li][g * 8];
      acc[nf] = __builtin_amdgcn_mfma_f32_16x16x32_bf16(a, b, acc[nf], 0, 0, 0);
    }
  }

  if (!vt) {
    #pragma unroll
    for (int nf = 0; nf < 4; ++nf)
      #pragma unroll
      for (int r = 0; r < 4; ++r) {
        int row = m0 + wave * 16 + g * 4 + r;   // global row in 0..4095
        int col = n0 + nf * 16 + li;            // output channel 0..1023
        int b_ = row >> 11, s_ = row & 2047;
        int h = col >> 6, dp = col & 63;
        Yh[((size_t)(b_ * NHB + h) * SB + s_) * DHB + dp] = f2bf(acc[nf][r]);
      }
  } else {
    // tile -> LDS (s_local, dp), then transposed store Vt[bh][dp][s]
    #pragma unroll
    for (int nf = 0; nf < 4; ++nf)
      #pragma unroll
      for (int r = 0; r < 4; ++r)
        Tlds[wave * 16 + g * 4 + r][nf * 16 + li] = f2bf(acc[nf][r]);
    __syncthreads();
    int dp = tid >> 2, sseg = tid & 3;
    short8 o0, o1;
    #pragma unroll
    for (int j = 0; j < 8; ++j) {
      o0[j] = (short)Tlds[sseg * 16 + j][dp];
      o1[j] = (short)Tlds[sseg * 16 + 8 + j][dp];
    }
    int h = n0 >> 6, b_ = m0 >> 11, s0 = m0 & 2047;
    unsigned short* dst = Yh + ((size_t)(b_ * NHB + h) * DHB + dp) * SB + s0 + sseg * 16;
    *(short8*)dst = o0;
    *(short8*)(dst + 8) = o1;
  }
}

// ---------------- K2: flash-style attention + attn materialization ----------
// grid (16 qtiles of 128, 32 bh), block 256 (4 waves; wave owns 32 q-rows)
__global__ __launch_bounds__(256) void attn_kernel(
    const unsigned short* __restrict__ Qh, const unsigned short* __restrict__ Kh,
    const unsigned short* __restrict__ Vt, const int* __restrict__ valid_len,
    float* __restrict__ attn_out, unsigned short* __restrict__ Mg)
{
  __shared__ unsigned short Klds[64][72];
  __shared__ unsigned short Vlds[64][72];   // V^T tile: [dp][key_local]
  __shared__ unsigned short QP[128][72];    // Q tile, later P tile

  const int tid = threadIdx.x;
  const int wave = tid >> 6, lane = tid & 63;
  const int g = lane >> 4, li = lane & 15;
  const int q0 = blockIdx.x * 128;
  const int bh = blockIdx.y;
  const int b_ = bh >> 4;
  const int vl = valid_len[b_];
  const int nkt = min(32, (vl + 63) >> 6);

  // stage Q tile (128 rows x 64 dh, bf16)
  {
    int qr = tid >> 1, half = (tid & 1) * 32;
    const unsigned short* src = Qh + ((size_t)bh * SB + q0 + qr) * DHB + half;
    #pragma unroll
    for (int j = 0; j < 4; ++j)
      *(short8*)&QP[qr][half + j * 8] = *(const short8*)(src + j * 8);
  }
  __syncthreads();

  short8 qa[2][2];   // [qf][ks]
  #pragma unroll
  for (int qf = 0; qf < 2; ++qf)
    #pragma unroll
    for (int ks = 0; ks < 2; ++ks)
      qa[qf][ks] = *(const short8*)&QP[wave * 32 + qf * 16 + li][ks * 32 + g * 8];

  float mrow[2][4], lrow[2][4];
  #pragma unroll
  for (int qf = 0; qf < 2; ++qf)
    #pragma unroll
    for (int r = 0; r < 4; ++r) { mrow[qf][r] = -1e30f; lrow[qf][r] = 0.f; }

  // ---- pass 1: per-lane online (m, l), only tiles with real keys ----
  for (int kti = 0; kti < nkt; ++kti) {
    const int kt = kti * 64;
    __syncthreads();
    {
      int kr = tid >> 2, cs = (tid & 3) * 16;
      const unsigned short* src = Kh + ((size_t)bh * SB + kt + kr) * DHB + cs;
      *(short8*)&Klds[kr][cs]     = *(const short8*)src;
      *(short8*)&Klds[kr][cs + 8] = *(const short8*)(src + 8);
    }
    __syncthreads();
    f32x4 sc[2][4];
    #pragma unroll
    for (int qf = 0; qf < 2; ++qf)
      #pragma unroll
      for (int nf = 0; nf < 4; ++nf)
        #pragma unroll
        for (int j = 0; j < 4; ++j) sc[qf][nf][j] = 0.f;
    #pragma unroll
    for (int ks = 0; ks < 2; ++ks)
      #pragma unroll
      for (int nf = 0; nf < 4; ++nf) {
        short8 kb = *(const short8*)&Klds[nf * 16 + li][ks * 32 + g * 8];
        #pragma unroll
        for (int qf = 0; qf < 2; ++qf)
          sc[qf][nf] = __builtin_amdgcn_mfma_f32_16x16x32_bf16(qa[qf][ks], kb, sc[qf][nf], 0, 0, 0);
      }
    #pragma unroll
    for (int qf = 0; qf < 2; ++qf)
      #pragma unroll
      for (int r = 0; r < 4; ++r) {
        float sv[4], tm = -1e30f;
        #pragma unroll
        for (int nf = 0; nf < 4; ++nf) {
          int key = kt + nf * 16 + li;
          float s = sc[qf][nf][r] * 0.125f;
          s = (key < vl) ? s : -1e6f;
          sv[nf] = s;
          tm = fmaxf(tm, s);
        }
        float mo = mrow[qf][r];
        float mn = fmaxf(mo, tm);
        float la = lrow[qf][r] * __expf(mo - mn);
        #pragma unroll
        for (int nf = 0; nf < 4; ++nf) la += __expf(sv[nf] - mn);
        lrow[qf][r] = la;
        mrow[qf][r] = mn;
      }
  }

  // cross-lane (16-lane group) reduce of (m, l)
  float rl[2][4];
  #pragma unroll
  for (int qf = 0; qf < 2; ++qf)
    #pragma unroll
    for (int r = 0; r < 4; ++r) {
      float M = mrow[qf][r];
      #pragma unroll
      for (int d = 1; d < 16; d <<= 1) M = fmaxf(M, __shfl_xor(M, d));
      float L = lrow[qf][r] * __expf(mrow[qf][r] - M);
      #pragma unroll
      for (int d = 1; d < 16; d <<= 1) L += __shfl_xor(L, d);
      mrow[qf][r] = M;
      rl[qf][r] = 1.f / L;
    }

  f32x4 oacc[2][4];
  #pragma unroll
  for (int qf = 0; qf < 2; ++qf)
    #pragma unroll
    for (int nf = 0; nf < 4; ++nf)
      #pragma unroll
      for (int j = 0; j < 4; ++j) oacc[qf][nf][j] = 0.f;

  // ---- pass 2: p, attn write, PV (compute tiles only) ----
  for (int kti = 0; kti < nkt; ++kti) {
    const int kt = kti * 64;
    __syncthreads();
    {
      int kr = tid >> 2, cs = (tid & 3) * 16;
      const unsigned short* src = Kh + ((size_t)bh * SB + kt + kr) * DHB + cs;
      *(short8*)&Klds[kr][cs]     = *(const short8*)src;
      *(short8*)&Klds[kr][cs + 8] = *(const short8*)(src + 8);
      const unsigned short* vs = Vt + ((size_t)bh * DHB + kr) * SB + kt + cs;
      *(short8*)&Vlds[kr][cs]     = *(const short8*)vs;
      *(short8*)&Vlds[kr][cs + 8] = *(const short8*)(vs + 8);
    }
    __syncthreads();
    f32x4 sc[2][4];
    #pragma unroll
    for (int qf = 0; qf < 2; ++qf)
      #pragma unroll
      for (int nf = 0; nf < 4; ++nf)
        #pragma unroll
        for (int j = 0; j < 4; ++j) sc[qf][nf][j] = 0.f;
    #pragma unroll
    for (int ks = 0; ks < 2; ++ks)
      #pragma unroll
      for (int nf = 0; nf < 4; ++nf) {
        short8 kb = *(const short8*)&Klds[nf * 16 + li][ks * 32 + g * 8];
        #pragma unroll
        for (int qf = 0; qf < 2; ++qf)
          sc[qf][nf] = __builtin_amdgcn_mfma_f32_16x16x32_bf16(qa[qf][ks], kb, sc[qf][nf], 0, 0, 0);
      }
    #pragma unroll
    for (int qf = 0; qf < 2; ++qf)
      #pragma unroll
      for (int nf = 0; nf < 4; ++nf)
        #pragma unroll
        for (int r = 0; r < 4; ++r) {
          int key = kt + nf * 16 + li;
          float s = sc[qf][nf][r] * 0.125f;
          s = (key < vl) ? s : -1e6f;
          float p = __expf(s - mrow[qf][r]) * rl[qf][r];
          int qrow = q0 + wave * 32 + qf * 16 + g * 4 + r;
          __builtin_nontemporal_store(
              p, attn_out + (size_t)bh * SB * SB + (size_t)qrow * SB + key);
          QP[wave * 32 + qf * 16 + g * 4 + r][nf * 16 + li] = f2bf(p);
        }
    __syncthreads();
    // PV: oacc += P(32x64) @ V(64x64) per wave
    #pragma unroll
    for (int ks = 0; ks < 2; ++ks) {
      short8 vb[4];
      #pragma unroll
      for (int nf = 0; nf < 4; ++nf)
        vb[nf] = *(const short8*)&Vlds[nf * 16 + li][ks * 32 + g * 8];
      #pragma unroll
      for (int qf = 0; qf < 2; ++qf) {
        short8 pa = *(const short8*)&QP[wave * 32 + qf * 16 + li][ks * 32 + g * 8];
        #pragma unroll
        for (int nf = 0; nf < 4; ++nf)
          oacc[qf][nf] = __builtin_amdgcn_mfma_f32_16x16x32_bf16(pa, vb[nf], oacc[qf][nf], 0, 0, 0);
      }
    }
  }

  // ---- zero-fill the masked tail of attn ----
  {
    int c0 = nkt * 64;
    int rem4 = (SB - c0) >> 2;
    if (rem4 > 0) {
      f32x4 z;
      z[0] = 0.f; z[1] = 0.f; z[2] = 0.f; z[3] = 0.f;
      for (int row = 0; row < 128; ++row) {
        float* dst = attn_out + (size_t)bh * SB * SB + (size_t)(q0 + row) * SB + c0;
        for (int c = tid; c < rem4; c += 256)
          __builtin_nontemporal_store(z, (f32x4*)dst + c);
      }
    }
  }

  // epilogue: merged[b, s, dp*nh + h] = O  (faithful Merge_base_head permutation)
  const int h = bh & 15;
  #pragma unroll
  for (int qf = 0; qf < 2; ++qf)
    #pragma unroll
    for (int nf = 0; nf < 4; ++nf)
      #pragma unroll
      for (int r = 0; r < 4; ++r) {
        int qrow = q0 + wave * 32 + qf * 16 + g * 4 + r;
        int dp = nf * 16 + li;
        Mg[((size_t)b_ * SB + qrow) * DB + dp * NHB + h] = f2bf(oacc[qf][nf][r]);
      }
}

// ---------------- K3: out = merged @ Wo.T, fp32 out ----------------
__global__ __launch_bounds__(256) void outproj_kernel(
    const unsigned short* __restrict__ Mg, const float* __restrict__ W,
    float* __restrict__ Out)
{
  __shared__ unsigned short Alds[64][40];
  __shared__ unsigned short Blds[64][40];
  const int tid = threadIdx.x;
  const int wave = tid >> 6, lane = tid & 63;
  const int g = lane >> 4, li = lane & 15;
  const int m0 = blockIdx.x * 64, n0 = blockIdx.y * 64;
  const int lr = tid >> 2, lseg = tid & 3;

  f32x4 acc[4];
  #pragma unroll
  for (int i = 0; i < 4; ++i)
    #pragma unroll
    for (int j = 0; j < 4; ++j) acc[i][j] = 0.f;

  for (int k0 = 0; k0 < DB; k0 += 32) {
    __syncthreads();
    {
      const unsigned short* sa = Mg + (size_t)(m0 + lr) * DB + k0 + lseg * 8;
      *(short8*)&Alds[lr][lseg * 8] = *(const short8*)sa;
      const float* sb = W + (size_t)(n0 + lr) * DB + k0 + lseg * 8;
      short8 tb;
      #pragma unroll
      for (int j = 0; j < 8; ++j) tb[j] = (short)f2bf(sb[j]);
      *(short8*)&Blds[lr][lseg * 8] = tb;
    }
    __syncthreads();
    short8 a = *(const short8*)&Alds[wave * 16 + li][g * 8];
    #pragma unroll
    for (int nf = 0; nf < 4; ++nf) {
      short8 b = *(const short8*)&Blds[nf * 16 + li][g * 8];
      acc[nf] = __builtin_amdgcn_mfma_f32_16x16x32_bf16(a, b, acc[nf], 0, 0, 0);
    }
  }
  #pragma unroll
  for (int nf = 0; nf < 4; ++nf)
    #pragma unroll
    for (int r = 0; r < 4; ++r) {
      int row = m0 + wave * 16 + g * 4 + r;
      int col = n0 + nf * 16 + li;
      Out[(size_t)row * DB + col] = acc[nf][r];
    }
}

extern "C" void kernel_launch(void* const* d_in, const int* in_sizes, int n_in,
                              void* d_out, int out_size, void* d_ws, size_t ws_size,
                              hipStream_t stream) {
  const float* q  = (const float*)d_in[0];
  const float* k  = (const float*)d_in[1];
  const float* v  = (const float*)d_in[2];
  const float* Wq = (const float*)d_in[3];
  const float* Wk = (const float*)d_in[4];
  const float* Wv = (const float*)d_in[5];
  const float* Wo = (const float*)d_in[6];
  const int* vlen = (const int*)d_in[7];

  const size_t hsz = (size_t)2 * NHB * SB * DHB;  // 4,194,304 elems per tensor
  unsigned short* Qh = (unsigned short*)d_ws;
  unsigned short* Kh = Qh + hsz;
  unsigned short* Vt = Kh + hsz;
  unsigned short* Mg = Vt + hsz;

  float* out  = (float*)d_out;
  float* attn = out + (size_t)2 * SB * DB;

  dim3 blk(256);
  proj_kernel<<<dim3(64, 16), blk, 0, stream>>>(q, Wq, Qh, 0);
  proj_kernel<<<dim3(64, 16), blk, 0, stream>>>(k, Wk, Kh, 0);
  proj_kernel<<<dim3(64, 16), blk, 0, stream>>>(v, Wv, Vt, 1);
  attn_kernel<<<dim3(16, 32), blk, 0, stream>>>(Qh, Kh, Vt, vlen, attn, Mg);
  outproj_kernel<<<dim3(64, 16), blk, 0, stream>>>(Mg, Wo, out);
}

// Round 3
// 248.934 us; speedup vs baseline: 1.5465x; 1.1355x over previous
//
#include <hip/hip_runtime.h>
#include <stdint.h>

#define SB 2048
#define DB 1024
#define NHB 16
#define DHB 64

typedef __attribute__((ext_vector_type(8))) short short8;
typedef __attribute__((ext_vector_type(4))) float f32x4;

__device__ __forceinline__ unsigned short f2bf(float f) {
  union { float f; uint32_t u; } v; v.f = f;
  uint32_t u = v.u;
  return (unsigned short)((u + 0x7FFFu + ((u >> 16) & 1u)) >> 16);
}

__device__ __forceinline__ void gld16(const void* g, void* l) {
  __builtin_amdgcn_global_load_lds(
      (const __attribute__((address_space(1))) void*)g,
      (__attribute__((address_space(3))) void*)l, 16, 0, 0);
}

__device__ __forceinline__ int xcd_swz(int bid, int nwg) {
  // bijective when nwg % 8 == 0
  return (bid & 7) * (nwg >> 3) + (bid >> 3);
}

// ---------------- K0: fp32 -> bf16 convert (7 tensors) ----------------
struct ConvArgs {
  const float* s[7];
  unsigned short* d[7];
  int n[7];
};

__global__ __launch_bounds__(256) void conv_kernel(ConvArgs a) {
  const int t = blockIdx.y;
  const float* __restrict__ src = a.s[t];
  unsigned short* __restrict__ dst = a.d[t];
  const int n8 = a.n[t] >> 3;
  for (int i = blockIdx.x * 256 + threadIdx.x; i < n8; i += gridDim.x * 256) {
    const f32x4* p = (const f32x4*)src + (size_t)i * 2;
    f32x4 x = p[0], y = p[1];
    short8 o;
    o[0] = (short)f2bf(x[0]); o[1] = (short)f2bf(x[1]);
    o[2] = (short)f2bf(x[2]); o[3] = (short)f2bf(x[3]);
    o[4] = (short)f2bf(y[0]); o[5] = (short)f2bf(y[1]);
    o[6] = (short)f2bf(y[2]); o[7] = (short)f2bf(y[3]);
    *(short8*)(dst + (size_t)i * 8) = o;
  }
}

// ---------------- K1: fused QKV projection GEMM (bf16 in, bf16 out) --------
// A: 4096x1024 bf16, B: 1024x1024 bf16 (rows = out channels). Tile 128Mx64N,
// BK=64, 4 waves (2x2), global_load_lds w/ XOR-swizzled source.
// z=0,1: head-split epilogue (Qh/Kh). z=2: transposed epilogue (Vt).
struct ProjArgs {
  const unsigned short* A[3];
  const unsigned short* B[3];
  unsigned short* O[3];
};

__global__ __launch_bounds__(256) void proj_gemm(ProjArgs pa) {
  __shared__ unsigned short SH[12288];   // Ab 128x64 | Bb 64x64 (linear, swizzled)
  unsigned short* Ab = SH;
  unsigned short* Bb = SH + 8192;

  const int z = blockIdx.y;
  const unsigned short* __restrict__ A = pa.A[z];
  const unsigned short* __restrict__ Bw = pa.B[z];
  unsigned short* __restrict__ O = pa.O[z];

  const int tid = threadIdx.x;
  const int w = tid >> 6, lane = tid & 63;
  const int g = lane >> 4, li = lane & 15;
  const int wm = w >> 1, wn = w & 1;
  const int l = xcd_swz(blockIdx.x, 512);
  const int m0 = (l >> 4) * 128, n0 = (l & 15) * 64;

  const int srow = lane >> 3;           // row within 8-row chunk
  const int sg = (lane & 7) ^ srow;     // inverse-swizzled source granule

  int a_off[4][2], b_off[2][2];
  #pragma unroll
  for (int mf = 0; mf < 4; ++mf) {
    int row = wm * 64 + mf * 16 + li;
    #pragma unroll
    for (int ks = 0; ks < 2; ++ks)
      a_off[mf][ks] = row * 64 + (((ks * 4 + g) ^ (li & 7)) << 3);
  }
  #pragma unroll
  for (int nf = 0; nf < 2; ++nf) {
    int row = wn * 32 + nf * 16 + li;
    #pragma unroll
    for (int ks = 0; ks < 2; ++ks)
      b_off[nf][ks] = row * 64 + (((ks * 4 + g) ^ (li & 7)) << 3);
  }

  f32x4 acc[4][2];
  #pragma unroll
  for (int i = 0; i < 4; ++i)
    #pragma unroll
    for (int j = 0; j < 2; ++j)
      #pragma unroll
      for (int e = 0; e < 4; ++e) acc[i][j][e] = 0.f;

  for (int k0 = 0; k0 < DB; k0 += 64) {
    __syncthreads();
    #pragma unroll
    for (int i = 0; i < 4; ++i) {
      int c = w * 4 + i;
      gld16(A + (size_t)(m0 + c * 8 + srow) * DB + k0 + sg * 8, Ab + c * 512);
    }
    #pragma unroll
    for (int i = 0; i < 2; ++i) {
      int c = w * 2 + i;
      gld16(Bw + (size_t)(n0 + c * 8 + srow) * DB + k0 + sg * 8, Bb + c * 512);
    }
    __syncthreads();
    short8 af[4][2], bf[2][2];
    #pragma unroll
    for (int mf = 0; mf < 4; ++mf)
      #pragma unroll
      for (int ks = 0; ks < 2; ++ks)
        af[mf][ks] = *(const short8*)&Ab[a_off[mf][ks]];
    #pragma unroll
    for (int nf = 0; nf < 2; ++nf)
      #pragma unroll
      for (int ks = 0; ks < 2; ++ks)
        bf[nf][ks] = *(const short8*)&Bb[b_off[nf][ks]];
    #pragma unroll
    for (int ks = 0; ks < 2; ++ks)
      #pragma unroll
      for (int mf = 0; mf < 4; ++mf)
        #pragma unroll
        for (int nf = 0; nf < 2; ++nf)
          acc[mf][nf] = __builtin_amdgcn_mfma_f32_16x16x32_bf16(
              af[mf][ks], bf[nf][ks], acc[mf][nf], 0, 0, 0);
  }

  const int h = n0 >> 6;
  if (z < 2) {
    #pragma unroll
    for (int mf = 0; mf < 4; ++mf)
      #pragma unroll
      for (int nf = 0; nf < 2; ++nf)
        #pragma unroll
        for (int r = 0; r < 4; ++r) {
          int row = m0 + wm * 64 + mf * 16 + g * 4 + r;
          int col = n0 + wn * 32 + nf * 16 + li;
          int b_ = row >> 11, s_ = row & 2047, dp = col & 63;
          O[((size_t)(b_ * NHB + h) * SB + s_) * DHB + dp] = f2bf(acc[mf][nf][r]);
        }
  } else {
    __syncthreads();
    #pragma unroll
    for (int mf = 0; mf < 4; ++mf)
      #pragma unroll
      for (int nf = 0; nf < 2; ++nf)
        #pragma unroll
        for (int r = 0; r < 4; ++r)
          SH[(wm * 64 + mf * 16 + g * 4 + r) * 72 + wn * 32 + nf * 16 + li] =
              f2bf(acc[mf][nf][r]);
    __syncthreads();
    int dp = tid >> 2, ss = tid & 3;
    int b_ = m0 >> 11, s0 = (m0 & 2047) + ss * 32;
    unsigned short* dst = O + ((size_t)(b_ * NHB + h) * DHB + dp) * SB + s0;
    #pragma unroll
    for (int j2 = 0; j2 < 4; ++j2) {
      short8 o;
      #pragma unroll
      for (int j = 0; j < 8; ++j) o[j] = (short)SH[(ss * 32 + j2 * 8 + j) * 72 + dp];
      *(short8*)(dst + j2 * 8) = o;
    }
  }
}

// ---------------- K2: flash-style attention + attn materialization ----------
__global__ __launch_bounds__(256) void attn_kernel(
    const unsigned short* __restrict__ Qh, const unsigned short* __restrict__ Kh,
    const unsigned short* __restrict__ Vt, const int* __restrict__ valid_len,
    float* __restrict__ attn_out, unsigned short* __restrict__ Mg)
{
  __shared__ unsigned short Klds[64][72];
  __shared__ unsigned short Vlds[64][72];   // V^T tile: [dp][key_local]
  __shared__ unsigned short QP[128][72];    // Q tile, later P tile

  const int tid = threadIdx.x;
  const int wave = tid >> 6, lane = tid & 63;
  const int g = lane >> 4, li = lane & 15;
  const int lsw = xcd_swz(blockIdx.x, 512);
  const int q0 = (lsw & 15) * 128;
  const int bh = lsw >> 4;
  const int b_ = bh >> 4;
  const int vl = valid_len[b_];
  const int nkt = min(32, (vl + 63) >> 6);

  // stage Q tile (128 rows x 64 dh, bf16)
  {
    int qr = tid >> 1, half = (tid & 1) * 32;
    const unsigned short* src = Qh + ((size_t)bh * SB + q0 + qr) * DHB + half;
    #pragma unroll
    for (int j = 0; j < 4; ++j)
      *(short8*)&QP[qr][half + j * 8] = *(const short8*)(src + j * 8);
  }
  __syncthreads();

  short8 qa[2][2];   // [qf][ks]
  #pragma unroll
  for (int qf = 0; qf < 2; ++qf)
    #pragma unroll
    for (int ks = 0; ks < 2; ++ks)
      qa[qf][ks] = *(const short8*)&QP[wave * 32 + qf * 16 + li][ks * 32 + g * 8];

  float mrow[2][4], lrow[2][4];
  #pragma unroll
  for (int qf = 0; qf < 2; ++qf)
    #pragma unroll
    for (int r = 0; r < 4; ++r) { mrow[qf][r] = -1e30f; lrow[qf][r] = 0.f; }

  // ---- pass 1: per-lane online (m, l) over real key tiles only ----
  for (int kti = 0; kti < nkt; ++kti) {
    const int kt = kti * 64;
    __syncthreads();
    {
      int kr = tid >> 2, cs = (tid & 3) * 16;
      const unsigned short* src = Kh + ((size_t)bh * SB + kt + kr) * DHB + cs;
      *(short8*)&Klds[kr][cs]     = *(const short8*)src;
      *(short8*)&Klds[kr][cs + 8] = *(const short8*)(src + 8);
    }
    __syncthreads();
    f32x4 sc[2][4];
    #pragma unroll
    for (int qf = 0; qf < 2; ++qf)
      #pragma unroll
      for (int nf = 0; nf < 4; ++nf)
        #pragma unroll
        for (int j = 0; j < 4; ++j) sc[qf][nf][j] = 0.f;
    #pragma unroll
    for (int ks = 0; ks < 2; ++ks)
      #pragma unroll
      for (int nf = 0; nf < 4; ++nf) {
        short8 kb = *(const short8*)&Klds[nf * 16 + li][ks * 32 + g * 8];
        #pragma unroll
        for (int qf = 0; qf < 2; ++qf)
          sc[qf][nf] = __builtin_amdgcn_mfma_f32_16x16x32_bf16(qa[qf][ks], kb, sc[qf][nf], 0, 0, 0);
      }
    #pragma unroll
    for (int qf = 0; qf < 2; ++qf)
      #pragma unroll
      for (int r = 0; r < 4; ++r) {
        float sv[4], tm = -1e30f;
        #pragma unroll
        for (int nf = 0; nf < 4; ++nf) {
          int key = kt + nf * 16 + li;
          float s = sc[qf][nf][r] * 0.125f;
          s = (key < vl) ? s : -1e6f;
          sv[nf] = s;
          tm = fmaxf(tm, s);
        }
        float mo = mrow[qf][r];
        float mn = fmaxf(mo, tm);
        float la = lrow[qf][r] * __expf(mo - mn);
        #pragma unroll
        for (int nf = 0; nf < 4; ++nf) la += __expf(sv[nf] - mn);
        lrow[qf][r] = la;
        mrow[qf][r] = mn;
      }
  }

  // cross-lane (16-lane group) reduce of (m, l)
  float rl[2][4];
  #pragma unroll
  for (int qf = 0; qf < 2; ++qf)
    #pragma unroll
    for (int r = 0; r < 4; ++r) {
      float M = mrow[qf][r];
      #pragma unroll
      for (int d = 1; d < 16; d <<= 1) M = fmaxf(M, __shfl_xor(M, d));
      float L = lrow[qf][r] * __expf(mrow[qf][r] - M);
      #pragma unroll
      for (int d = 1; d < 16; d <<= 1) L += __shfl_xor(L, d);
      mrow[qf][r] = M;
      rl[qf][r] = 1.f / L;
    }

  f32x4 oacc[2][4];
  #pragma unroll
  for (int qf = 0; qf < 2; ++qf)
    #pragma unroll
    for (int nf = 0; nf < 4; ++nf)
      #pragma unroll
      for (int j = 0; j < 4; ++j) oacc[qf][nf][j] = 0.f;

  // ---- pass 2: p, attn write, PV ----
  for (int kti = 0; kti < nkt; ++kti) {
    const int kt = kti * 64;
    __syncthreads();
    {
      int kr = tid >> 2, cs = (tid & 3) * 16;
      const unsigned short* src = Kh + ((size_t)bh * SB + kt + kr) * DHB + cs;
      *(short8*)&Klds[kr][cs]     = *(const short8*)src;
      *(short8*)&Klds[kr][cs + 8] = *(const short8*)(src + 8);
      const unsigned short* vs = Vt + ((size_t)bh * DHB + kr) * SB + kt + cs;
      *(short8*)&Vlds[kr][cs]     = *(const short8*)vs;
      *(short8*)&Vlds[kr][cs + 8] = *(const short8*)(vs + 8);
    }
    __syncthreads();
    f32x4 sc[2][4];
    #pragma unroll
    for (int qf = 0; qf < 2; ++qf)
      #pragma unroll
      for (int nf = 0; nf < 4; ++nf)
        #pragma unroll
        for (int j = 0; j < 4; ++j) sc[qf][nf][j] = 0.f;
    #pragma unroll
    for (int ks = 0; ks < 2; ++ks)
      #pragma unroll
      for (int nf = 0; nf < 4; ++nf) {
        short8 kb = *(const short8*)&Klds[nf * 16 + li][ks * 32 + g * 8];
        #pragma unroll
        for (int qf = 0; qf < 2; ++qf)
          sc[qf][nf] = __builtin_amdgcn_mfma_f32_16x16x32_bf16(qa[qf][ks], kb, sc[qf][nf], 0, 0, 0);
      }
    #pragma unroll
    for (int qf = 0; qf < 2; ++qf)
      #pragma unroll
      for (int nf = 0; nf < 4; ++nf)
        #pragma unroll
        for (int r = 0; r < 4; ++r) {
          int key = kt + nf * 16 + li;
          float s = sc[qf][nf][r] * 0.125f;
          s = (key < vl) ? s : -1e6f;
          float p = __expf(s - mrow[qf][r]) * rl[qf][r];
          int qrow = q0 + wave * 32 + qf * 16 + g * 4 + r;
          __builtin_nontemporal_store(
              p, attn_out + (size_t)bh * SB * SB + (size_t)qrow * SB + key);
          QP[wave * 32 + qf * 16 + g * 4 + r][nf * 16 + li] = f2bf(p);
        }
    __syncthreads();
    #pragma unroll
    for (int ks = 0; ks < 2; ++ks) {
      short8 vb[4];
      #pragma unroll
      for (int nf = 0; nf < 4; ++nf)
        vb[nf] = *(const short8*)&Vlds[nf * 16 + li][ks * 32 + g * 8];
      #pragma unroll
      for (int qf = 0; qf < 2; ++qf) {
        short8 pa = *(const short8*)&QP[wave * 32 + qf * 16 + li][ks * 32 + g * 8];
        #pragma unroll
        for (int nf = 0; nf < 4; ++nf)
          oacc[qf][nf] = __builtin_amdgcn_mfma_f32_16x16x32_bf16(pa, vb[nf], oacc[qf][nf], 0, 0, 0);
      }
    }
  }

  // ---- zero-fill the masked tail of attn ----
  {
    int c0 = nkt * 64;
    int rem4 = (SB - c0) >> 2;
    if (rem4 > 0) {
      f32x4 z;
      z[0] = 0.f; z[1] = 0.f; z[2] = 0.f; z[3] = 0.f;
      for (int row = 0; row < 128; ++row) {
        float* dst = attn_out + (size_t)bh * SB * SB + (size_t)(q0 + row) * SB + c0;
        for (int c = tid; c < rem4; c += 256)
          __builtin_nontemporal_store(z, (f32x4*)dst + c);
      }
    }
  }

  // epilogue: merged[b, s, dp*nh + h] = O
  const int h = bh & 15;
  #pragma unroll
  for (int qf = 0; qf < 2; ++qf)
    #pragma unroll
    for (int nf = 0; nf < 4; ++nf)
      #pragma unroll
      for (int r = 0; r < 4; ++r) {
        int qrow = q0 + wave * 32 + qf * 16 + g * 4 + r;
        int dp = nf * 16 + li;
        Mg[((size_t)b_ * SB + qrow) * DB + dp * NHB + h] = f2bf(oacc[qf][nf][r]);
      }
}

// ---------------- K3: out = merged @ Wo.T, fp32 out (same GEMM core) -------
__global__ __launch_bounds__(256) void out_gemm(
    const unsigned short* __restrict__ A, const unsigned short* __restrict__ Bw,
    float* __restrict__ Out)
{
  __shared__ unsigned short SH[12288];
  unsigned short* Ab = SH;
  unsigned short* Bb = SH + 8192;

  const int tid = threadIdx.x;
  const int w = tid >> 6, lane = tid & 63;
  const int g = lane >> 4, li = lane & 15;
  const int wm = w >> 1, wn = w & 1;
  const int l = xcd_swz(blockIdx.x, 512);
  const int m0 = (l >> 4) * 128, n0 = (l & 15) * 64;

  const int srow = lane >> 3;
  const int sg = (lane & 7) ^ srow;

  int a_off[4][2], b_off[2][2];
  #pragma unroll
  for (int mf = 0; mf < 4; ++mf) {
    int row = wm * 64 + mf * 16 + li;
    #pragma unroll
    for (int ks = 0; ks < 2; ++ks)
      a_off[mf][ks] = row * 64 + (((ks * 4 + g) ^ (li & 7)) << 3);
  }
  #pragma unroll
  for (int nf = 0; nf < 2; ++nf) {
    int row = wn * 32 + nf * 16 + li;
    #pragma unroll
    for (int ks = 0; ks < 2; ++ks)
      b_off[nf][ks] = row * 64 + (((ks * 4 + g) ^ (li & 7)) << 3);
  }

  f32x4 acc[4][2];
  #pragma unroll
  for (int i = 0; i < 4; ++i)
    #pragma unroll
    for (int j = 0; j < 2; ++j)
      #pragma unroll
      for (int e = 0; e < 4; ++e) acc[i][j][e] = 0.f;

  for (int k0 = 0; k0 < DB; k0 += 64) {
    __syncthreads();
    #pragma unroll
    for (int i = 0; i < 4; ++i) {
      int c = w * 4 + i;
      gld16(A + (size_t)(m0 + c * 8 + srow) * DB + k0 + sg * 8, Ab + c * 512);
    }
    #pragma unroll
    for (int i = 0; i < 2; ++i) {
      int c = w * 2 + i;
      gld16(Bw + (size_t)(n0 + c * 8 + srow) * DB + k0 + sg * 8, Bb + c * 512);
    }
    __syncthreads();
    short8 af[4][2], bf[2][2];
    #pragma unroll
    for (int mf = 0; mf < 4; ++mf)
      #pragma unroll
      for (int ks = 0; ks < 2; ++ks)
        af[mf][ks] = *(const short8*)&Ab[a_off[mf][ks]];
    #pragma unroll
    for (int nf = 0; nf < 2; ++nf)
      #pragma unroll
      for (int ks = 0; ks < 2; ++ks)
        bf[nf][ks] = *(const short8*)&Bb[b_off[nf][ks]];
    #pragma unroll
    for (int ks = 0; ks < 2; ++ks)
      #pragma unroll
      for (int mf = 0; mf < 4; ++mf)
        #pragma unroll
        for (int nf = 0; nf < 2; ++nf)
          acc[mf][nf] = __builtin_amdgcn_mfma_f32_16x16x32_bf16(
              af[mf][ks], bf[nf][ks], acc[mf][nf], 0, 0, 0);
  }

  #pragma unroll
  for (int mf = 0; mf < 4; ++mf)
    #pragma unroll
    for (int nf = 0; nf < 2; ++nf)
      #pragma unroll
      for (int r = 0; r < 4; ++r) {
        int row = m0 + wm * 64 + mf * 16 + g * 4 + r;
        int col = n0 + wn * 32 + nf * 16 + li;
        Out[(size_t)row * DB + col] = acc[mf][nf][r];
      }
}

extern "C" void kernel_launch(void* const* d_in, const int* in_sizes, int n_in,
                              void* d_out, int out_size, void* d_ws, size_t ws_size,
                              hipStream_t stream) {
  const float* q  = (const float*)d_in[0];
  const float* k  = (const float*)d_in[1];
  const float* v  = (const float*)d_in[2];
  const float* Wq = (const float*)d_in[3];
  const float* Wk = (const float*)d_in[4];
  const float* Wv = (const float*)d_in[5];
  const float* Wo = (const float*)d_in[6];
  const int* vlen = (const int*)d_in[7];

  const size_t HS = (size_t)2 * NHB * SB * DHB;  // 4,194,304
  const size_t WS = (size_t)DB * DB;             // 1,048,576

  unsigned short* ws = (unsigned short*)d_ws;
  unsigned short* qb  = ws;
  unsigned short* kb  = qb + HS;
  unsigned short* vb  = kb + HS;
  unsigned short* Wqb = vb + HS;
  unsigned short* Wkb = Wqb + WS;
  unsigned short* Wvb = Wkb + WS;
  unsigned short* Wob = Wvb + WS;
  unsigned short* Qh  = Wob + WS;
  unsigned short* Kh  = Qh + HS;
  unsigned short* Vt  = Kh + HS;
  unsigned short* Mg  = qb;   // qb dead after proj; reuse for merged output

  float* out  = (float*)d_out;
  float* attn = out + (size_t)2 * SB * DB;

  ConvArgs ca;
  ca.s[0] = q;  ca.d[0] = qb;  ca.n[0] = (int)HS;
  ca.s[1] = k;  ca.d[1] = kb;  ca.n[1] = (int)HS;
  ca.s[2] = v;  ca.d[2] = vb;  ca.n[2] = (int)HS;
  ca.s[3] = Wq; ca.d[3] = Wqb; ca.n[3] = (int)WS;
  ca.s[4] = Wk; ca.d[4] = Wkb; ca.n[4] = (int)WS;
  ca.s[5] = Wv; ca.d[5] = Wvb; ca.n[5] = (int)WS;
  ca.s[6] = Wo; ca.d[6] = Wob; ca.n[6] = (int)WS;

  ProjArgs pa;
  pa.A[0] = qb;  pa.A[1] = kb;  pa.A[2] = vb;
  pa.B[0] = Wqb; pa.B[1] = Wkb; pa.B[2] = Wvb;
  pa.O[0] = Qh;  pa.O[1] = Kh;  pa.O[2] = Vt;

  dim3 blk(256);
  conv_kernel<<<dim3(1024, 7), blk, 0, stream>>>(ca);
  proj_gemm<<<dim3(512, 3), blk, 0, stream>>>(pa);
  attn_kernel<<<dim3(512), blk, 0, stream>>>(Qh, Kh, Vt, vlen, attn, Mg);
  out_gemm<<<dim3(512), blk, 0, stream>>>(Mg, Wob, out);
}